// Round 1
// baseline (141.578 us; speedup 1.0000x reference)
//
#include <hip/hip_runtime.h>

// Problem constants
#define NIMG 4
#define CCH  3
#define KCH  21
#define HIN  128
#define WIN  128
#define OH   64
#define OW   64
#define PPX  (OH*OW)      // 4096 pixels after 0.5x downsample
#define REC  32           // floats per packed record (5 feat + 21 seg + 6 pad)

// Tiling
#define BLOCK 256
#define IT    4                 // i-records per thread
#define ITILE (BLOCK*IT)        // 1024 i per block
#define JT    128               // j-chunk per block
#define JC    (PPX/JT)          // 32 j-chunks

// ---------------------------------------------------------------------------
// Prep: downsample + pack per-pixel records into ws.
// rec[0..4]  = [x/50, y/50, r/0.15, g/0.15, b/0.15]
// rec[5..25] = 2x2-avg-pooled seg * nearest ROI
// ---------------------------------------------------------------------------
__global__ void crf_prep(const float* __restrict__ img,
                         const float* __restrict__ seg,
                         const float* __restrict__ roi,
                         float* __restrict__ ws) {
    int idx = blockIdx.x * blockDim.x + threadIdx.x;   // [0, NIMG*PPX)
    int n = idx / PPX;
    int p = idx % PPX;
    int y = p / OW, x = p % OW;
    int y2 = 2 * y, x2 = 2 * x;

    float* rec = ws + (size_t)(n * PPX + p) * REC;

    const float inv_sxy  = 1.0f / 50.0f;    // SIGMA_XY * SCALE = 50
    const float inv_srgb = 1.0f / 0.15f;

    rec[0] = (float)x * inv_sxy;
    rec[1] = (float)y * inv_sxy;
#pragma unroll
    for (int c = 0; c < CCH; ++c)
        rec[2 + c] = img[(((size_t)n * CCH + c) * HIN + y2) * WIN + x2] * inv_srgb;

    float r = roi[((size_t)n * HIN + y2) * WIN + x2];

#pragma unroll
    for (int k = 0; k < KCH; ++k) {
        const float* s0 = seg + (((size_t)n * KCH + k) * HIN + y2) * WIN + x2;
        // bilinear 2x down with align_corners=False => exact 2x2 average pool
        float v = 0.25f * (s0[0] + s0[1] + s0[WIN] + s0[WIN + 1]);
        rec[5 + k] = v * r;
    }
#pragma unroll
    for (int q = 26; q < REC; ++q) rec[q] = 0.0f;
}

// ---------------------------------------------------------------------------
// Main: fused pairwise  sum_{i,j} exp(-0.5*d2)* <s_i,s_j>
// ---------------------------------------------------------------------------
__global__ __launch_bounds__(BLOCK) void crf_main(const float* __restrict__ ws,
                                                  float* __restrict__ out) {
    const int cj = blockIdx.x;   // j-chunk
    const int ti = blockIdx.y;   // i-tile
    const int n  = blockIdx.z;   // image

    const float4* base = (const float4*)ws + (size_t)n * PPX * (REC / 4);

    __shared__ float4 tile[JT * (REC / 4)];   // 16 KB
    __shared__ float  wsum[BLOCK / 64];

    // stage j-chunk into LDS (coalesced float4)
    const int j0 = cj * JT;
    for (int v = threadIdx.x; v < JT * (REC / 4); v += BLOCK)
        tile[v] = base[(size_t)j0 * (REC / 4) + v];

    // load i-records into registers
    float4 ri[IT][7];
    float  acc[IT];
#pragma unroll
    for (int it = 0; it < IT; ++it) {
        int i = ti * ITILE + it * BLOCK + threadIdx.x;
        const float4* rp = base + (size_t)i * (REC / 4);
#pragma unroll
        for (int q = 0; q < 7; ++q) ri[it][q] = rp[q];
        acc[it] = 0.0f;
    }
    __syncthreads();

#pragma unroll 2
    for (int j = 0; j < JT; ++j) {
        float4 bb[7];
#pragma unroll
        for (int q = 0; q < 7; ++q) bb[q] = tile[j * (REC / 4) + q];
        const float* vj = (const float*)bb;

#pragma unroll
        for (int it = 0; it < IT; ++it) {
            const float* fi = (const float*)ri[it];
            float dx0 = fi[0] - vj[0];
            float dx1 = fi[1] - vj[1];
            float dx2 = fi[2] - vj[2];
            float dx3 = fi[3] - vj[3];
            float dx4 = fi[4] - vj[4];
            float dA = dx0 * dx0 + dx2 * dx2;
            float dB = dx1 * dx1 + dx3 * dx3;
            dA += dx4 * dx4;
            float w = __expf(-0.5f * (dA + dB));

            float e0 = 0.0f, e1 = 0.0f;
#pragma unroll
            for (int k = 5; k < 26; k += 2) e0 += fi[k] * vj[k];
#pragma unroll
            for (int k = 6; k < 26; k += 2) e1 += fi[k] * vj[k];
            acc[it] += w * (e0 + e1);
        }
    }

    // reduce: thread -> wave -> block -> global atomic
    float tot = (acc[0] + acc[1]) + (acc[2] + acc[3]);
#pragma unroll
    for (int off = 32; off > 0; off >>= 1) tot += __shfl_down(tot, off);

    const int lane = threadIdx.x & 63;
    const int wid  = threadIdx.x >> 6;
    if (lane == 0) wsum[wid] = tot;
    __syncthreads();
    if (threadIdx.x == 0) {
        float s = 0.0f;
#pragma unroll
        for (int w = 0; w < BLOCK / 64; ++w) s += wsum[w];
        // out = WEIGHT * (-sum/NIMG) = -5e-10 * sum
        atomicAdd(out, s * (-5.0e-10f));
    }
}

extern "C" void kernel_launch(void* const* d_in, const int* in_sizes, int n_in,
                              void* d_out, int out_size, void* d_ws, size_t ws_size,
                              hipStream_t stream) {
    const float* img = (const float*)d_in[0];
    const float* seg = (const float*)d_in[1];
    const float* roi = (const float*)d_in[2];
    float* out = (float*)d_out;
    float* ws  = (float*)d_ws;   // needs 4*4096*32*4 = 2 MB

    hipMemsetAsync(out, 0, sizeof(float), stream);

    crf_prep<<<(NIMG * PPX) / BLOCK, BLOCK, 0, stream>>>(img, seg, roi, ws);

    dim3 grid(JC, PPX / ITILE, NIMG);
    crf_main<<<grid, BLOCK, 0, stream>>>(ws, out);
}

// Round 2
// 127.532 us; speedup vs baseline: 1.1101x; 1.1101x over previous
//
#include <hip/hip_runtime.h>

// Problem constants
#define NIMG 4
#define CCH  3
#define KCH  21
#define HIN  128
#define WIN  128
#define OH   64
#define OW   64
#define PPX  (OH*OW)      // 4096 pixels after 0.5x downsample
#define REC  32           // floats per packed record (5 feat + 21 seg + 6 pad)

// Tiling
#define BLOCK 256
#define IT    4                 // i-records per thread
#define ITILE (BLOCK*IT)        // 1024 i per block
#define JT    128               // j-chunk per block

// feature prescale: sqrt(0.5*log2(e)) so that w = exp2(-sum dx'^2) = exp(-0.5*d2)
#define PRE 0.84932180f

// ---------------------------------------------------------------------------
// Prep: one thread per record ELEMENT (32 per pixel) for parallelism +
// coalesced writes.  rec[0..4] = prescaled [x/50, y/50, rgb/0.15],
// rec[5..25] = 2x2-avg-pooled seg * nearest ROI, rec[26..31] = 0.
// ---------------------------------------------------------------------------
__global__ __launch_bounds__(BLOCK) void crf_prep(const float* __restrict__ img,
                                                  const float* __restrict__ seg,
                                                  const float* __restrict__ roi,
                                                  float* __restrict__ ws) {
    int g = blockIdx.x * BLOCK + threadIdx.x;      // [0, NIMG*PPX*REC)
    int q = g & (REC - 1);
    int pl = g >> 5;                               // linear pixel [0, NIMG*PPX)
    int n = pl / PPX;
    int p = pl % PPX;
    int y = p / OW, x = p % OW;
    int y2 = 2 * y, x2 = 2 * x;

    float val = 0.0f;
    if (q < 2) {
        val = (float)(q == 0 ? x : y) * ((1.0f / 50.0f) * PRE);
    } else if (q < 5) {
        int c = q - 2;
        val = img[(((size_t)n * CCH + c) * HIN + y2) * WIN + x2] * ((1.0f / 0.15f) * PRE);
    } else if (q < 26) {
        int k = q - 5;
        const float* s0 = seg + (((size_t)n * KCH + k) * HIN + y2) * WIN + x2;
        float v = 0.25f * (s0[0] + s0[1] + s0[WIN] + s0[WIN + 1]);
        float r = roi[((size_t)n * HIN + y2) * WIN + x2];
        val = v * r;
    }
    ws[(size_t)pl * REC + q] = val;
}

// ---------------------------------------------------------------------------
// Main: fused pairwise  sum_{i<=j} [2 or 1] * exp2(-sum dx'^2) * <s_i,s_j>
// Block = (i-tile of 1024) x (j-chunk of 128); only chunks with j-range
// reaching the diagonal or above are launched (80 per image instead of 128).
// ---------------------------------------------------------------------------
__global__ __launch_bounds__(BLOCK, 2) void crf_main(const float* __restrict__ ws,
                                                     float* __restrict__ out) {
    // decode blockIdx.x in [0,80) -> (ti, cj) with cj >= 8*ti
    int bx = blockIdx.x;
    const int n = blockIdx.y;
    int ti, cj;
    if (bx < 32)      { ti = 0; cj = bx; }
    else if (bx < 56) { ti = 1; cj = bx - 32 + 8; }
    else if (bx < 72) { ti = 2; cj = bx - 56 + 16; }
    else              { ti = 3; cj = bx - 72 + 24; }
    const bool diag = (cj < ti * 8 + 8);   // j-chunk overlaps i-tile

    const float4* base = (const float4*)ws + (size_t)n * PPX * (REC / 4);

    __shared__ float4 tile[JT * (REC / 4)];   // 16 KB
    __shared__ float  wsum[BLOCK / 64];

    // stage j-chunk into LDS (coalesced float4)
    const int j0 = cj * JT;
    for (int v = threadIdx.x; v < JT * (REC / 4); v += BLOCK)
        tile[v] = base[(size_t)j0 * (REC / 4) + v];

    // load i-records into registers
    const int i0 = ti * ITILE;
    float4 ri[IT][7];
    float  acc[IT];
    int    ig[IT];
#pragma unroll
    for (int it = 0; it < IT; ++it) {
        int i = i0 + it * BLOCK + threadIdx.x;
        ig[it] = i;
        const float4* rp = base + (size_t)i * (REC / 4);
#pragma unroll
        for (int qq = 0; qq < 7; ++qq) ri[it][qq] = rp[qq];
        acc[it] = 0.0f;
    }
    __syncthreads();

    if (!diag) {
        // strictly-upper block: every pair has j > i, uniform weight 2
        // (folded into the final scale)
#pragma unroll 2
        for (int j = 0; j < JT; ++j) {
            float4 bb[7];
#pragma unroll
            for (int qq = 0; qq < 7; ++qq) bb[qq] = tile[j * (REC / 4) + qq];
            const float* vj = (const float*)bb;
#pragma unroll
            for (int it = 0; it < IT; ++it) {
                const float* fi = (const float*)ri[it];
                float dx0 = fi[0] - vj[0];
                float dx1 = fi[1] - vj[1];
                float dx2 = fi[2] - vj[2];
                float dx3 = fi[3] - vj[3];
                float dx4 = fi[4] - vj[4];
                float d = dx0 * dx0;
                d = fmaf(dx1, dx1, d);
                d = fmaf(dx2, dx2, d);
                d = fmaf(dx3, dx3, d);
                d = fmaf(dx4, dx4, d);
                float w = __builtin_amdgcn_exp2f(-d);
                float e = fi[5] * vj[5];
#pragma unroll
                for (int k = 6; k < 26; ++k) e = fmaf(fi[k], vj[k], e);
                acc[it] = fmaf(w, e, acc[it]);
            }
        }
    } else {
        // diagonal-straddling block: per-pair weight 2/1/0
#pragma unroll 2
        for (int j = 0; j < JT; ++j) {
            float4 bb[7];
#pragma unroll
            for (int qq = 0; qq < 7; ++qq) bb[qq] = tile[j * (REC / 4) + qq];
            const float* vj = (const float*)bb;
            const int jg = j0 + j;
#pragma unroll
            for (int it = 0; it < IT; ++it) {
                const float* fi = (const float*)ri[it];
                float dx0 = fi[0] - vj[0];
                float dx1 = fi[1] - vj[1];
                float dx2 = fi[2] - vj[2];
                float dx3 = fi[3] - vj[3];
                float dx4 = fi[4] - vj[4];
                float d = dx0 * dx0;
                d = fmaf(dx1, dx1, d);
                d = fmaf(dx2, dx2, d);
                d = fmaf(dx3, dx3, d);
                d = fmaf(dx4, dx4, d);
                float w = __builtin_amdgcn_exp2f(-d);
                float e = fi[5] * vj[5];
#pragma unroll
                for (int k = 6; k < 26; ++k) e = fmaf(fi[k], vj[k], e);
                float wf = (jg > ig[it]) ? 2.0f : ((jg == ig[it]) ? 1.0f : 0.0f);
                acc[it] = fmaf(w * wf, e, acc[it]);
            }
        }
    }

    // reduce: thread -> wave -> block -> global atomic
    float tot = (acc[0] + acc[1]) + (acc[2] + acc[3]);
#pragma unroll
    for (int off = 32; off > 0; off >>= 1) tot += __shfl_down(tot, off);

    const int lane = threadIdx.x & 63;
    const int wid  = threadIdx.x >> 6;
    if (lane == 0) wsum[wid] = tot;
    __syncthreads();
    if (threadIdx.x == 0) {
        float s = 0.0f;
#pragma unroll
        for (int w = 0; w < BLOCK / 64; ++w) s += wsum[w];
        // out = WEIGHT * (-sum/NIMG) = -5e-10 * sum; pure-upper blocks carry x2
        float scale = diag ? -5.0e-10f : -1.0e-9f;
        atomicAdd(out, s * scale);
    }
}

extern "C" void kernel_launch(void* const* d_in, const int* in_sizes, int n_in,
                              void* d_out, int out_size, void* d_ws, size_t ws_size,
                              hipStream_t stream) {
    const float* img = (const float*)d_in[0];
    const float* seg = (const float*)d_in[1];
    const float* roi = (const float*)d_in[2];
    float* out = (float*)d_out;
    float* ws  = (float*)d_ws;   // needs 4*4096*32*4 = 2 MB

    hipMemsetAsync(out, 0, sizeof(float), stream);

    crf_prep<<<(NIMG * PPX * REC) / BLOCK, BLOCK, 0, stream>>>(img, seg, roi, ws);

    dim3 grid(80, NIMG);
    crf_main<<<grid, BLOCK, 0, stream>>>(ws, out);
}

// Round 3
// 101.084 us; speedup vs baseline: 1.4006x; 1.2616x over previous
//
#include <hip/hip_runtime.h>

// Problem constants
#define NIMG 4
#define CCH  3
#define KCH  21
#define HIN  128
#define WIN  128
#define OH   64
#define OW   64
#define PPX  (OH*OW)      // 4096 pixels after 0.5x downsample
#define REC  32           // floats per packed record (5 feat + 21 seg + 6 pad)

// Tiling
#define BLOCK 256
#define IT    2                 // i-records per thread
#define ITILE (BLOCK*IT)        // 512 i per block
#define JT    64                // j-chunk per block
#define NTI   (PPX/ITILE)       // 8 i-tiles
#define NCJ   (PPX/JT)          // 64 j-chunks

// feature prescale: sqrt(0.5*log2(e)) so that w = exp2(-sum dx'^2) = exp(-0.5*d2)
#define PRE 0.84932180f

// ---------------------------------------------------------------------------
// Prep: one thread per record ELEMENT (32 per pixel); coalesced writes.
// Thread g==0 also zeroes the output accumulator (main runs after in stream
// order, so this replaces the separate memset node).
// ---------------------------------------------------------------------------
__global__ __launch_bounds__(BLOCK) void crf_prep(const float* __restrict__ img,
                                                  const float* __restrict__ seg,
                                                  const float* __restrict__ roi,
                                                  float* __restrict__ ws,
                                                  float* __restrict__ out) {
    int g = blockIdx.x * BLOCK + threadIdx.x;      // [0, NIMG*PPX*REC)
    if (g == 0) out[0] = 0.0f;
    int q = g & (REC - 1);
    int pl = g >> 5;                               // linear pixel [0, NIMG*PPX)
    int n = pl / PPX;
    int p = pl % PPX;
    int y = p / OW, x = p % OW;
    int y2 = 2 * y, x2 = 2 * x;

    float val = 0.0f;
    if (q < 2) {
        val = (float)(q == 0 ? x : y) * ((1.0f / 50.0f) * PRE);
    } else if (q < 5) {
        int c = q - 2;
        val = img[(((size_t)n * CCH + c) * HIN + y2) * WIN + x2] * ((1.0f / 0.15f) * PRE);
    } else if (q < 26) {
        int k = q - 5;
        const float* s0 = seg + (((size_t)n * KCH + k) * HIN + y2) * WIN + x2;
        float v = 0.25f * (s0[0] + s0[1] + s0[WIN] + s0[WIN + 1]);
        float r = roi[((size_t)n * HIN + y2) * WIN + x2];
        val = v * r;
    }
    ws[(size_t)pl * REC + q] = val;
}

// ---------------------------------------------------------------------------
// Main: fused pairwise  sum_{i<=j} [2 or 1] * exp2(-sum dx'^2) * <s_i,s_j>
// Block = (i-tile of 512) x (j-chunk of 64); only chunks whose j-range is not
// entirely below the i-tile are launched: 288 blocks/image, 1152 total.
// ---------------------------------------------------------------------------
__global__ __launch_bounds__(BLOCK, 4) void crf_main(const float* __restrict__ ws,
                                                     float* __restrict__ out) {
    // decode blockIdx.x in [0,288) -> (ti, cj) with cj >= 8*ti
    int bx = blockIdx.x;
    const int n = blockIdx.y;
    int ti = 0;
#pragma unroll
    for (int t = 1; t < NTI; ++t) {
        // offset[t] = sum_{u<t} (NCJ - 8u) = 64t - 4t(t-1)
        int off = NCJ * t - 4 * t * (t - 1);
        if (bx >= off) ti = t;
    }
    int base_off = NCJ * ti - 4 * ti * (ti - 1);
    int cj = (bx - base_off) + 8 * ti;
    const bool diag = (cj < 8 * ti + 8);   // j-chunk overlaps i-tile

    const float4* base = (const float4*)ws + (size_t)n * PPX * (REC / 4);

    __shared__ float4 tile[JT * (REC / 4)];   // 8 KB
    __shared__ float  wsum[BLOCK / 64];

    // stage j-chunk into LDS (coalesced float4)
    const int j0 = cj * JT;
    for (int v = threadIdx.x; v < JT * (REC / 4); v += BLOCK)
        tile[v] = base[(size_t)j0 * (REC / 4) + v];

    // load i-records into registers
    const int i0 = ti * ITILE;
    float4 ri[IT][7];
    float  acc[IT];
    int    ig[IT];
#pragma unroll
    for (int it = 0; it < IT; ++it) {
        int i = i0 + it * BLOCK + threadIdx.x;
        ig[it] = i;
        const float4* rp = base + (size_t)i * (REC / 4);
#pragma unroll
        for (int qq = 0; qq < 7; ++qq) ri[it][qq] = rp[qq];
        acc[it] = 0.0f;
    }
    __syncthreads();

    if (!diag) {
        // strictly-upper block: every pair has j > i; weight 2 folded into scale
#pragma unroll 2
        for (int j = 0; j < JT; ++j) {
            float4 bb[7];
#pragma unroll
            for (int qq = 0; qq < 7; ++qq) bb[qq] = tile[j * (REC / 4) + qq];
            const float* vj = (const float*)bb;
#pragma unroll
            for (int it = 0; it < IT; ++it) {
                const float* fi = (const float*)ri[it];
                float dx0 = fi[0] - vj[0];
                float dx1 = fi[1] - vj[1];
                float dx2 = fi[2] - vj[2];
                float dx3 = fi[3] - vj[3];
                float dx4 = fi[4] - vj[4];
                float d = dx0 * dx0;
                d = fmaf(dx1, dx1, d);
                d = fmaf(dx2, dx2, d);
                d = fmaf(dx3, dx3, d);
                d = fmaf(dx4, dx4, d);
                float w = __builtin_amdgcn_exp2f(-d);
                float e = fi[5] * vj[5];
#pragma unroll
                for (int k = 6; k < 26; ++k) e = fmaf(fi[k], vj[k], e);
                acc[it] = fmaf(w, e, acc[it]);
            }
        }
    } else {
        // diagonal-straddling block: per-pair weight 2/1/0
#pragma unroll 2
        for (int j = 0; j < JT; ++j) {
            float4 bb[7];
#pragma unroll
            for (int qq = 0; qq < 7; ++qq) bb[qq] = tile[j * (REC / 4) + qq];
            const float* vj = (const float*)bb;
            const int jg = j0 + j;
#pragma unroll
            for (int it = 0; it < IT; ++it) {
                const float* fi = (const float*)ri[it];
                float dx0 = fi[0] - vj[0];
                float dx1 = fi[1] - vj[1];
                float dx2 = fi[2] - vj[2];
                float dx3 = fi[3] - vj[3];
                float dx4 = fi[4] - vj[4];
                float d = dx0 * dx0;
                d = fmaf(dx1, dx1, d);
                d = fmaf(dx2, dx2, d);
                d = fmaf(dx3, dx3, d);
                d = fmaf(dx4, dx4, d);
                float w = __builtin_amdgcn_exp2f(-d);
                float e = fi[5] * vj[5];
#pragma unroll
                for (int k = 6; k < 26; ++k) e = fmaf(fi[k], vj[k], e);
                float wf = (jg > ig[it]) ? 2.0f : ((jg == ig[it]) ? 1.0f : 0.0f);
                acc[it] = fmaf(w * wf, e, acc[it]);
            }
        }
    }

    // reduce: thread -> wave -> block -> global atomic
    float tot = acc[0] + acc[1];
#pragma unroll
    for (int off = 32; off > 0; off >>= 1) tot += __shfl_down(tot, off);

    const int lane = threadIdx.x & 63;
    const int wid  = threadIdx.x >> 6;
    if (lane == 0) wsum[wid] = tot;
    __syncthreads();
    if (threadIdx.x == 0) {
        float s = 0.0f;
#pragma unroll
        for (int w = 0; w < BLOCK / 64; ++w) s += wsum[w];
        // out = WEIGHT * (-sum/NIMG) = -5e-10 * sum; pure-upper blocks carry x2
        float scale = diag ? -5.0e-10f : -1.0e-9f;
        atomicAdd(out, s * scale);
    }
}

extern "C" void kernel_launch(void* const* d_in, const int* in_sizes, int n_in,
                              void* d_out, int out_size, void* d_ws, size_t ws_size,
                              hipStream_t stream) {
    const float* img = (const float*)d_in[0];
    const float* seg = (const float*)d_in[1];
    const float* roi = (const float*)d_in[2];
    float* out = (float*)d_out;
    float* ws  = (float*)d_ws;   // needs 4*4096*32*4 = 2 MB

    crf_prep<<<(NIMG * PPX * REC) / BLOCK, BLOCK, 0, stream>>>(img, seg, roi, ws, out);

    dim3 grid(NIMG * 0 + 288, NIMG);   // 288 triangular blocks per image
    crf_main<<<grid, BLOCK, 0, stream>>>(ws, out);
}

// Round 4
// 95.832 us; speedup vs baseline: 1.4774x; 1.0548x over previous
//
#include <hip/hip_runtime.h>

// Problem constants
#define NIMG 4
#define CCH  3
#define KCH  21
#define HIN  128
#define WIN  128
#define OH   64
#define OW   64
#define PPX  (OH*OW)          // 4096 pixels after 0.5x downsample
#define PRE  0.84932180f      // sqrt(0.5*log2(e)): exp(-0.5 d2) == exp2(-|f'i-f'j|^2)

#define SEGW  24              // halfs per pixel: 21 seg + 3 zero (48B, 16B-aligned)
#define FEATW 8               // halfs per pixel: 5 feat + 3 zero (16B)

#define BLOCK  256
#define JCHUNK 256            // j-pixels staged per block
#define IBLK   64             // i-pixels per block (16 per wave)

typedef _Float16 half_t;
typedef half_t half8  __attribute__((ext_vector_type(8)));
typedef float  f32x4v __attribute__((ext_vector_type(4)));

// ws layout (bytes): segH | featH | sqF   (total ~1.06 MB)
#define FEATH_OFF ((size_t)NIMG*PPX*SEGW*2)
#define SQF_OFF   (FEATH_OFF + (size_t)NIMG*PPX*FEATW*2)

// ---------------------------------------------------------------------------
// Prep: per (pixel, q) thread. q<24 -> seg channel (2x2 avg pool * nearest
// ROI) as f16; q==24 -> 5 prescaled features as f16 (padded half8) + fp32
// |f|^2 (computed from the f16-ROUNDED values so E_ii == 0 exactly).
// Thread 0 zeroes the output accumulator.
// ---------------------------------------------------------------------------
__global__ __launch_bounds__(BLOCK) void crf_prep(const float* __restrict__ img,
                                                  const float* __restrict__ seg,
                                                  const float* __restrict__ roi,
                                                  half_t* __restrict__ segH,
                                                  half_t* __restrict__ featH,
                                                  float* __restrict__ sqF,
                                                  float* __restrict__ out) {
    int g = blockIdx.x * BLOCK + threadIdx.x;     // [0, NIMG*PPX*32)
    if (g == 0) out[0] = 0.0f;
    int q  = g & 31;
    int pl = g >> 5;                              // linear pixel [0, NIMG*PPX)
    int n  = pl >> 12;
    int p  = pl & (PPX - 1);
    int y = p >> 6, x = p & 63;
    int y2 = 2 * y, x2 = 2 * x;

    if (q < SEGW) {
        float v = 0.0f;
        if (q < KCH) {
            const float* s0 = seg + (((size_t)n * KCH + q) * HIN + y2) * WIN + x2;
            float r = roi[((size_t)n * HIN + y2) * WIN + x2];
            v = 0.25f * (s0[0] + s0[1] + s0[WIN] + s0[WIN + 1]) * r;
        }
        segH[(size_t)pl * SEGW + q] = (half_t)v;
    } else if (q == 24) {
        float fx = (float)x * (PRE / 50.0f);
        float fy = (float)y * (PRE / 50.0f);
        const size_t ib = (((size_t)n * CCH) * HIN + y2) * WIN + x2;
        float fr = img[ib]                        * (PRE / 0.15f);
        float fg = img[ib + (size_t)HIN * WIN]    * (PRE / 0.15f);
        float fb = img[ib + 2 * (size_t)HIN * WIN] * (PRE / 0.15f);
        half_t h0 = (half_t)fx, h1 = (half_t)fy, h2 = (half_t)fr,
               h3 = (half_t)fg, h4 = (half_t)fb;
        half8 fh = {h0, h1, h2, h3, h4, (half_t)0, (half_t)0, (half_t)0};
        *(half8*)(featH + (size_t)pl * FEATW) = fh;
        float a0 = (float)h0, a1 = (float)h1, a2 = (float)h2,
              a3 = (float)h3, a4 = (float)h4;
        sqF[pl] = a0 * a0 + a1 * a1 + a2 * a2 + a3 * a3 + a4 * a4;
    }
}

// ---------------------------------------------------------------------------
// Main: per 16x16 pair tile, two mfma_f32_16x16x32_f16 Grams (seg, feat);
// epilogue: E = 2*Gf - sq_i - sq_j; term = exp2(E) * Gs.
// Verified layouts (learn_hip m89/m118): A/B: idx=lane&15, k=(lane>>4)*8+j;
// C/D: col=lane&15, row=(lane>>4)*4+reg.
// Triangular launch: block (I,J) with J >= I>>2; i-block in [64I,64I+64),
// j-chunk [256J,256J+256). Strictly-upper blocks weight 2 (folded in scale);
// diag blocks (J==I>>2) add log2-weight {+1,0,-inf} per pair.
// ---------------------------------------------------------------------------
__global__ __launch_bounds__(BLOCK) void crf_main(const half_t* __restrict__ segH,
                                                  const half_t* __restrict__ featH,
                                                  const float* __restrict__ sqF,
                                                  float* __restrict__ out) {
    const int bx = blockIdx.x;
    const int n  = blockIdx.y;

    // triangular decode: g = I>>2 group, count per group c = 16-g over 4 I's
    int g = 0;
#pragma unroll
    for (int t = 1; t < 16; ++t) {
        int off = 64 * t - 2 * t * (t - 1);
        if (bx >= off) g = t;
    }
    int rem = bx - (64 * g - 2 * g * (g - 1));
    int c   = 16 - g;
    int iq  = (rem >= c) + (rem >= 2 * c) + (rem >= 3 * c);
    int I   = 4 * g + iq;
    int J   = g + (rem - iq * c);
    const bool diag = (J == (I >> 2));

    const half_t* segN  = segH  + (size_t)n * PPX * SEGW;
    const half_t* featN = featH + (size_t)n * PPX * FEATW;
    const float*  sqN   = sqF   + (size_t)n * PPX;

    __shared__ alignas(16) half_t segJ[JCHUNK * SEGW];    // 12 KB
    __shared__ alignas(16) half_t featJ[JCHUNK * FEATW];  // 4 KB
    __shared__ float hJ[JCHUNK];                          // 1 KB
    __shared__ float wsum[BLOCK / 64];

    const int tid  = threadIdx.x;
    const int lane = tid & 63, wv = tid >> 6;
    const int m = lane & 15, quad = lane >> 4;
    const int i0 = I * IBLK + wv * 16;
    const int j0 = J * JCHUNK;
    const int kq = (quad < 2) ? quad : 2;   // seg k-slice (quad3 zeroed)

    half8 hz = {};

    // A-frags from global (once per block lifetime, reused over 16 j-tiles)
    half8 aseg  = *(const half8*)(segN  + (size_t)(i0 + m) * SEGW + kq * 8);
    half8 afeat = *(const half8*)(featN + (size_t)(i0 + m) * FEATW);
    f32x4v hi   = *(const f32x4v*)(sqN + i0 + quad * 4);  // rows quad*4..+3
    if (quad == 3) aseg  = hz;
    if (quad != 0) afeat = hz;
    f32x4v nh = -hi;

    // stage j-chunk (flat coalesced float4 copies; layouts match global)
    {
        const f32x4v* gsrc = (const f32x4v*)(segN + (size_t)j0 * SEGW);
        f32x4v* ldst = (f32x4v*)segJ;
#pragma unroll
        for (int v = 0; v < 3; ++v) ldst[tid + v * BLOCK] = gsrc[tid + v * BLOCK];
        ((f32x4v*)featJ)[tid] = ((const f32x4v*)(featN + (size_t)j0 * FEATW))[tid];
        hJ[tid] = sqN[j0 + tid];
    }
    __syncthreads();

    float racc = 0.0f;
    const f32x4v zero4 = {0.0f, 0.0f, 0.0f, 0.0f};

#pragma unroll 4
    for (int jt = 0; jt < JCHUNK / 16; ++jt) {
        const int jp = jt * 16 + m;
        half8 bseg  = *(const half8*)(segJ  + jp * SEGW + kq * 8);
        half8 bfeat = *(const half8*)(featJ + jp * FEATW);
        if (quad == 3) bseg  = hz;
        if (quad != 0) bfeat = hz;
        float hc = hJ[jp];

        f32x4v Gs = __builtin_amdgcn_mfma_f32_16x16x32_f16(aseg,  bseg,  zero4, 0, 0, 0);
        f32x4v Gf = __builtin_amdgcn_mfma_f32_16x16x32_f16(afeat, bfeat, zero4, 0, 0, 0);

        if (!diag) {
#pragma unroll
            for (int r = 0; r < 4; ++r) {
                float E = fmaf(2.0f, Gf[r], nh[r] - hc);
                racc = fmaf(__builtin_amdgcn_exp2f(E), Gs[r], racc);
            }
        } else {
            const int jg = j0 + jp;
#pragma unroll
            for (int r = 0; r < 4; ++r) {
                int ig = i0 + quad * 4 + r;
                float sel = (jg > ig) ? 1.0f : ((jg == ig) ? 0.0f : -100000.0f);
                float E = fmaf(2.0f, Gf[r], nh[r] - hc) + sel;
                racc = fmaf(__builtin_amdgcn_exp2f(E), Gs[r], racc);
            }
        }
    }

    // reduce: thread -> wave -> block -> global atomic
#pragma unroll
    for (int off = 32; off > 0; off >>= 1) racc += __shfl_down(racc, off);
    if (lane == 0) wsum[wv] = racc;
    __syncthreads();
    if (tid == 0) {
        float s = wsum[0] + wsum[1] + wsum[2] + wsum[3];
        // out = -5e-10 * full-sum; strictly-upper blocks carry the x2
        atomicAdd(out, s * (diag ? -5.0e-10f : -1.0e-9f));
    }
}

extern "C" void kernel_launch(void* const* d_in, const int* in_sizes, int n_in,
                              void* d_out, int out_size, void* d_ws, size_t ws_size,
                              hipStream_t stream) {
    const float* img = (const float*)d_in[0];
    const float* seg = (const float*)d_in[1];
    const float* roi = (const float*)d_in[2];
    float* out = (float*)d_out;

    char* wsb = (char*)d_ws;                    // uses ~1.06 MB of ws
    half_t* segH  = (half_t*)(wsb);
    half_t* featH = (half_t*)(wsb + FEATH_OFF);
    float*  sqF   = (float*)(wsb + SQF_OFF);

    crf_prep<<<(NIMG * PPX * 32) / BLOCK, BLOCK, 0, stream>>>(img, seg, roi,
                                                              segH, featH, sqF, out);

    dim3 grid(544, NIMG);                       // sum_g 4*(16-g) = 544 per image
    crf_main<<<grid, BLOCK, 0, stream>>>(segH, featH, sqF, out);
}